// Round 20
// baseline (78.284 us; speedup 1.0000x reference)
//
#include <hip/hip_runtime.h>

#define B_ 2048
#define N_ 1024
#define M_ 4
#define T_ 64
#define R_ 128
#define C_ 10

typedef _Float16 half2v __attribute__((ext_vector_type(2)));
typedef __fp16 fp16x2 __attribute__((ext_vector_type(2)));
typedef float float16v __attribute__((ext_vector_type(16)));
typedef float float2v __attribute__((ext_vector_type(2)));
typedef int int8v __attribute__((ext_vector_type(8)));
typedef unsigned short ushort_t;
typedef unsigned int uint_t;

#define ALPHA   1.171f
#define WENC    9.368f        /* 8 * ALPHA : folds A-scale 2^-3 and alpha into W codes */
#define UFK     1.0205e-5f    /* 0.25 * ALPHA^-64 : folds B-scale 2^-2 and alpha^-64 */

__device__ __forceinline__ uint_t pk16(float a, float b) {
    fp16x2 h = __builtin_amdgcn_cvt_pkrtz(a, b);
    return __builtin_bit_cast(uint_t, h);
}

// Preprocessing (R16/R19 verbatim — validated fragment maps).
// blocks [0,512): feature-map+average -> div16 (f16 pairs).
// blocks [512,592): flat gather w-pack to fp4 (e2m1) A-fragments for
// mfma_scale_32x32x64 fmt=4: dword j, byte q, nibble n <-> i = 64ks+32h+8j+2q+n;
// code = fp4(WENC * w_mid[c,i,m,o]), o = 32wv+(lane&31), h = lane>>5;
// frag = (c*4+wv)*8 + m*2 + ks, entry = wtA[frag*64 + lane] (uint4).
__global__ void k_pre(const float* __restrict__ tensor, const float* __restrict__ w_mid,
                      uint2* __restrict__ div16, uint4* __restrict__ wtA) {
    int tid = threadIdx.x;
    if (blockIdx.x < 512) {
        int gid = blockIdx.x * 256 + tid;            // 0 .. B*T-1
        int t = gid >> 11;
        int b = gid & 2047;
        const float4* tp = (const float4*)(tensor + b * N_ + t * 16);
        float a0 = 0.f, a1 = 0.f, a2 = 0.f, a3 = 0.f;
#pragma unroll
        for (int v = 0; v < 4; ++v) {
            float4 xv = tp[v];
            float xs[4] = {xv.x, xv.y, xv.z, xv.w};
#pragma unroll
            for (int p = 0; p < 4; ++p) {
                float ang = 1.57079632679f * xs[p];
                float s, c;
                __sincosf(ang, &s, &c);
                float c2 = c * c, s2 = s * s;
                a0 += c2 * c; a1 += c2 * s; a2 += c * s2; a3 += s2 * s;
            }
        }
        const float sc = 1.0f / 16.0f;
        uint2 o; o.x = pk16(a0 * sc, a1 * sc); o.y = pk16(a2 * sc, a3 * sc);
        div16[gid] = o;
    } else {
        int gid = (blockIdx.x - 512) * 256 + tid;    // 0 .. 20479
        int frag = gid >> 6;                         // 0 .. 319
        int lane = gid & 63;
        int c  = frag >> 5;
        int wv = (frag >> 3) & 3;
        int m  = (frag >> 1) & 3;
        int ks = frag & 1;
        int h = lane >> 5, o = wv * 32 + (lane & 31);
        uint_t dw[4];
#pragma unroll
        for (int j = 0; j < 4; ++j) {
            int base = 64 * ks + 32 * h + 8 * j;
            const float* p0 = w_mid + ((c * 128 + base + 0) * 4 + m) * 128 + o;
            const float* p1 = w_mid + ((c * 128 + base + 2) * 4 + m) * 128 + o;
            const float* p2 = w_mid + ((c * 128 + base + 4) * 4 + m) * 128 + o;
            const float* p3 = w_mid + ((c * 128 + base + 6) * 4 + m) * 128 + o;
            uint_t acc = 0;
            acc = __builtin_amdgcn_cvt_scalef32_pk_fp4_f32(acc, p0[0] * WENC, p0[512] * WENC, 1.0f, 0);
            acc = __builtin_amdgcn_cvt_scalef32_pk_fp4_f32(acc, p1[0] * WENC, p1[512] * WENC, 1.0f, 1);
            acc = __builtin_amdgcn_cvt_scalef32_pk_fp4_f32(acc, p2[0] * WENC, p2[512] * WENC, 1.0f, 2);
            acc = __builtin_amdgcn_cvt_scalef32_pk_fp4_f32(acc, p3[0] * WENC, p3[512] * WENC, 1.0f, 3);
            dw[j] = acc;
        }
        wtA[frag * 64 + lane] = make_uint4(dw[0], dw[1], dw[2], dw[3]);
    }
}

// 64-step recurrence: ONE WAVE = 32 samples, zero barriers (R19 structure).
// Adds: x software-pipeline (prefetch t+1 into regs) + packed-f32 fold.
__global__ void __launch_bounds__(64)
k_main(const uint2* __restrict__ div16, const uint4* __restrict__ wtA,
       const float* __restrict__ w_first, const float* __restrict__ w_last,
       float* __restrict__ logits) {
    __shared__ __align__(16) char st[2048];      // 16 dword-chunks x 32 b x 4 B

    const int lane = threadIdx.x;
    const int c  = blockIdx.y;
    const int b0 = blockIdx.x * 32;
    const int h = lane >> 5;       // k-half
    const int b31 = lane & 31;     // b col (B/D) == o col offset (A rows)

    // W fragments: 4 tiles x 4 m x 2 ks, 4 dwords each = 128 VGPRs.
    uint4 wfr[4][4][2];
    {
        const uint4* wb = wtA + (c * 4) * 8 * 64 + lane;
#pragma unroll
        for (int tl = 0; tl < 4; ++tl)
#pragma unroll
            for (int m = 0; m < 4; ++m)
#pragma unroll
                for (int ks = 0; ks < 2; ++ks)
                    wfr[tl][m][ks] = wb[(tl * 8 + m * 2 + ks) * 64];
    }

    // Initial state: s0[i] = sum_m w_first[c,0,m,i]; code = fp4(4*s0), all b.
    if (lane < 16) {
        float v[8];
#pragma unroll
        for (int n = 0; n < 8; ++n) {
            float s = 0.f;
#pragma unroll
            for (int m = 0; m < 4; ++m) s += w_first[(c * 4 + m) * 128 + lane * 8 + n];
            v[n] = 4.f * s;
        }
        uint_t pk = 0;
        pk = __builtin_amdgcn_cvt_scalef32_pk_fp4_f32(pk, v[0], v[1], 1.0f, 0);
        pk = __builtin_amdgcn_cvt_scalef32_pk_fp4_f32(pk, v[2], v[3], 1.0f, 1);
        pk = __builtin_amdgcn_cvt_scalef32_pk_fp4_f32(pk, v[4], v[5], 1.0f, 2);
        pk = __builtin_amdgcn_cvt_scalef32_pk_fp4_f32(pk, v[6], v[7], 1.0f, 3);
#pragma unroll
        for (int b = 0; b < 32; ++b)
            *(uint_t*)(st + lane * 128 + b * 4) = pk;
    }
    // No barrier: subsequent DS reads are later in this wave's program order.

    // T-invariant LDS byte offsets.
    int roff[2][4];                // B-operand dwords: chunk 8ks+4h+j
#pragma unroll
    for (int ks = 0; ks < 2; ++ks)
#pragma unroll
        for (int j = 0; j < 4; ++j)
            roff[ks][j] = (8 * ks + 4 * h + j) * 128 + b31 * 4;
    int woff[4][4];                // tile tl, reg-quad rb -> chunk 4tl+rb, byte 2h
#pragma unroll
    for (int tl = 0; tl < 4; ++tl)
#pragma unroll
        for (int rb = 0; rb < 4; ++rb)
            woff[tl][rb] = (4 * tl + rb) * 128 + b31 * 4 + 2 * h;

    const float16v z16 = (float16v)(0.0f);
    const uint2* xp = div16 + b0 + b31;

    uint2 xd = xp[0];                          // x(0) prefetched

    for (int t = 0; t < T_; ++t) {
        // Prefetch x(t+1) now — consumed next iteration (~1 full step later).
        int tn = (t + 1 < T_) ? (t + 1) : t;
        uint2 xd_next = xp[tn << 11];

        // Decode current x (off the load path) and pre-scale by 4.
        half2v xlo = __builtin_bit_cast(half2v, xd.x);
        half2v xhi = __builtin_bit_cast(half2v, xd.y);
        float x0 = 4.f * (float)xlo.x, x1 = 4.f * (float)xlo.y;
        float x2 = 4.f * (float)xhi.x, x3 = 4.f * (float)xhi.y;

        // State (B operands) — one read batch.
        int8v bv0 = (int8v){ *(const int*)(st + roff[0][0]), *(const int*)(st + roff[0][1]),
                             *(const int*)(st + roff[0][2]), *(const int*)(st + roff[0][3]), 0, 0, 0, 0 };
        int8v bv1 = (int8v){ *(const int*)(st + roff[1][0]), *(const int*)(st + roff[1][1]),
                             *(const int*)(st + roff[1][2]), *(const int*)(st + roff[1][3]), 0, 0, 0, 0 };

#pragma unroll
        for (int tl = 0; tl < 4; ++tl) {
            float16v am[4];
#pragma unroll
            for (int m = 0; m < 4; ++m) {
                uint4 w0 = wfr[tl][m][0], w1 = wfr[tl][m][1];
                int8v a0 = (int8v){(int)w0.x, (int)w0.y, (int)w0.z, (int)w0.w, 0, 0, 0, 0};
                int8v a1 = (int8v){(int)w1.x, (int)w1.y, (int)w1.z, (int)w1.w, 0, 0, 0, 0};
                am[m] = __builtin_amdgcn_mfma_scale_f32_32x32x64_f8f6f4(
                    a0, bv0, z16, 4, 4, 0, 124, 0, 125);
                am[m] = __builtin_amdgcn_mfma_scale_f32_32x32x64_f8f6f4(
                    a1, bv1, am[m], 4, 4, 0, 124, 0, 125);
            }
            // Fold (packed f32 pairs) + fp4 encode + write.
            // D: col=b31, row=(reg&3)+8*(reg>>2)+4h; reg quad rb:
            // rows 8rb+4h+e -> i = 32tl+8rb+4h+e -> chunk 4tl+rb, nibble 4h+e.
            union { float16v v; float2v p[8]; } A0, A1, A2, A3;
            A0.v = am[0]; A1.v = am[1]; A2.v = am[2]; A3.v = am[3];
#pragma unroll
            for (int rb = 0; rb < 4; ++rb) {
                float2v s01 = A0.p[2*rb]   * x0 + A1.p[2*rb]   * x1
                            + A2.p[2*rb]   * x2 + A3.p[2*rb]   * x3;
                float2v s23 = A0.p[2*rb+1] * x0 + A1.p[2*rb+1] * x1
                            + A2.p[2*rb+1] * x2 + A3.p[2*rb+1] * x3;
                uint_t pk = __builtin_amdgcn_cvt_scalef32_pk_fp4_f32(0u, s01.x, s01.y, 1.0f, 0);
                pk = __builtin_amdgcn_cvt_scalef32_pk_fp4_f32(pk, s23.x, s23.y, 1.0f, 1);
                *(ushort_t*)(st + woff[tl][rb]) = (ushort_t)(pk & 0xFFFFu);
            }
        }
        xd = xd_next;
        // No barrier: next iteration's DS reads follow these writes in order.
    }

    // Final contraction: logits[b,c] = sum_i state_true[b,i]*uf[i],
    // state_true = (code/4)*alpha^-64; uf[i] = UFK * sum_m w_last[c,i,m].
    {
        const float tbl[8] = {0.f, 0.5f, 1.f, 1.5f, 2.f, 3.f, 4.f, 6.f};
        float p = 0.f;
#pragma unroll
        for (int ks = 0; ks < 2; ++ks)
#pragma unroll
            for (int j = 0; j < 4; ++j) {
                uint_t dwv = *(const uint_t*)(st + roff[ks][j]);
#pragma unroll
                for (int nb = 0; nb < 8; ++nb) {
                    int i = 64 * ks + 32 * h + 8 * j + nb;
                    float4 wl4 = *(const float4*)(w_last + (c * 128 + i) * 4);
                    float ufi = UFK * (wl4.x + wl4.y + wl4.z + wl4.w);
                    int nib = (dwv >> (nb * 4)) & 0xF;
                    float mag = tbl[nib & 7];
                    p += (nib & 8 ? -mag : mag) * ufi;
                }
            }
        p += __shfl_xor(p, 32);
        if (h == 0) logits[(b0 + b31) * C_ + c] = p;
    }
}

// Log-softmax over C=10, output FLOAT32.
__global__ void k_lsm(const float* __restrict__ logits, float* __restrict__ out) {
    int b = blockIdx.x * 256 + threadIdx.x;
    float x[C_];
    float mx = -1e30f;
#pragma unroll
    for (int c = 0; c < C_; ++c) { x[c] = logits[b * C_ + c]; mx = fmaxf(mx, x[c]); }
    float s = 0.f;
#pragma unroll
    for (int c = 0; c < C_; ++c) s += __expf(x[c] - mx);
    float lse = mx + __logf(s);
#pragma unroll
    for (int c = 0; c < C_; ++c) out[b * C_ + c] = x[c] - lse;
}

extern "C" void kernel_launch(void* const* d_in, const int* in_sizes, int n_in,
                              void* d_out, int out_size, void* d_ws, size_t ws_size,
                              hipStream_t stream) {
    const float* tensor  = (const float*)d_in[0];   // (B,N)      f32
    const float* w_first = (const float*)d_in[1];   // (C,1,M,R)  f32
    const float* w_mid   = (const float*)d_in[2];   // (C,R,M,R)  f32
    const float* w_last  = (const float*)d_in[3];   // (C,R,M,1)  f32
    char* ws = (char*)d_ws;
    uint2* div16 = (uint2*)ws;                               // 1 MiB
    uint4* wtA   = (uint4*)(ws + 1048576);                   // 320 KB (fp4)
    float* logits = (float*)(ws + 1048576 + 327680);         // 80 KB
    float* out = (float*)d_out;                              // (B,C) f32

    k_pre<<<592, 256, 0, stream>>>(tensor, w_mid, div16, wtA);
    k_main<<<dim3(64, 10), 64, 0, stream>>>(div16, wtA, w_first, w_last, logits);
    k_lsm<<<8, 256, 0, stream>>>(logits, out);
}